// Round 9
// baseline (544.201 us; speedup 1.0000x reference)
//
#include <hip/hip_runtime.h>
#include <hip/hip_bf16.h>

#define M_PTS 512
#define D_CLS 10
#define S_DIM 16384
#define K_DIM 1024
#define DIN_  784
#define PHI_ELEMS (5120 * 1024)

typedef short  bf16x8  __attribute__((ext_vector_type(8)));
typedef float  f32x4   __attribute__((ext_vector_type(4)));
typedef ushort ushort8 __attribute__((ext_vector_type(8)));

__device__ __forceinline__ ushort f2bfu(float f) {
    __bf16 h = (__bf16)f;                 // hardware RNE cvt on gfx950
    return __builtin_bit_cast(ushort, h);
}
__device__ __forceinline__ float bfu2f(ushort u) {
    uint x = (uint)u << 16;
    return __builtin_bit_cast(float, x);
}

// ---------------- mean = X @ W  (512x784 @ 784x10) ----------------
__global__ __launch_bounds__(64) void mean_kernel(const float* __restrict__ X,
                                                  const float* __restrict__ W,
                                                  float* __restrict__ out) {
    int m = blockIdx.x;
    int lane = threadIdx.x;
    float acc[D_CLS];
#pragma unroll
    for (int d = 0; d < D_CLS; ++d) acc[d] = 0.f;
    for (int i = lane; i < DIN_; i += 64) {
        float x = X[(size_t)m * DIN_ + i];
#pragma unroll
        for (int d = 0; d < D_CLS; ++d) acc[d] += x * W[i * D_CLS + d];
    }
#pragma unroll
    for (int d = 0; d < D_CLS; ++d) {
        float v = acc[d];
        for (int off = 32; off > 0; off >>= 1) v += __shfl_down(v, off);
        if (lane == 0) out[(size_t)m * D_CLS + d] = v;
    }
}

// ---------------- f32 -> bf16 streaming convert (n8 = elems/8) ---------------
__global__ __launch_bounds__(256) void cvt_a(const float* __restrict__ src,
                                             ushort* __restrict__ dst, int n8) {
    for (int i = blockIdx.x * 256 + threadIdx.x; i < n8; i += gridDim.x * 256) {
        float4 a = reinterpret_cast<const float4*>(src)[2 * i];
        float4 b = reinterpret_cast<const float4*>(src)[2 * i + 1];
        ushort8 o;
        o[0] = f2bfu(a.x); o[1] = f2bfu(a.y); o[2] = f2bfu(a.z); o[3] = f2bfu(a.w);
        o[4] = f2bfu(b.x); o[5] = f2bfu(b.y); o[6] = f2bfu(b.z); o[7] = f2bfu(b.w);
        reinterpret_cast<ushort8*>(dst)[i] = o;
    }
}

// ---------------- v (16384x1024 f32) -> vT (1024x16384 bf16) -----------------
__global__ __launch_bounds__(256) void cvt_bt(const float* __restrict__ v,
                                              ushort* __restrict__ bt) {
    __shared__ float tile[64][65];
    const int kt = blockIdx.x;   // 256 k-tiles
    const int ct = blockIdx.y;   // 16 col-tiles
    const int t  = threadIdx.x;
    const int col4 = t & 15, row = t >> 4;
#pragma unroll
    for (int i = 0; i < 4; ++i) {
        int r = row + 16 * i;
        float4 v4 = *reinterpret_cast<const float4*>(
            v + (size_t)(kt * 64 + r) * K_DIM + ct * 64 + col4 * 4);
        tile[r][col4 * 4 + 0] = v4.x; tile[r][col4 * 4 + 1] = v4.y;
        tile[r][col4 * 4 + 2] = v4.z; tile[r][col4 * 4 + 3] = v4.w;
    }
    __syncthreads();
#pragma unroll
    for (int i = 0; i < 2; ++i) {
        int cid = i * 256 + t;
        int c = cid >> 3, kc = cid & 7;
        ushort8 o;
#pragma unroll
        for (int j = 0; j < 8; ++j) o[j] = f2bfu(tile[kc * 8 + j][c]);
        *reinterpret_cast<ushort8*>(bt + (size_t)(ct * 64 + c) * S_DIM +
                                    kt * 64 + kc * 8) = o;
    }
}

// ---------------- gemm_bd: 128x128 tile, A via LDS-DMA, B direct-to-reg ------
// C(5120 x 1024) = A(5120 x 16384) x BT(1024 x 16384)^T, bf16 row-major.
// BK=32, 256 threads = 4 waves (2M x 2N), wave tile 64x64.
// A: conflict-free swizzled LDS (f(r)=(r>>1)&3, verified r6/r7), depth-3,
//    counted vmcnt (tile s+2 in flight across barriers).
// B: per-block panel (512 KB, L2-resident) -> fb frags loaded DIRECT from
//    global into regs, one step ahead (alternating reg sets b0/b1). Lanes
//    kq=0..3 of one row read 64 contiguous bytes -> line-coalesced.
// LDS traffic per block-step: 24 KB (vs 48 KB staged-B) — halves the binding
// resource identified r8 post-mortem.
// Writes bf16 partial slab kp.
template <int KSP>
__global__ __launch_bounds__(256, 3) void gemm_bd(const ushort* __restrict__ A,
                                                  const ushort* __restrict__ BT,
                                                  ushort* __restrict__ Cout) {
    __shared__ ushort As[3][4096];   // 8 KB per buf, 24 KB total

    const int nwg = 320 * KSP;
    const int lid = blockIdx.x;
    const int swz = (lid & 7) * (nwg >> 3) + (lid >> 3);   // bijective XCD swizzle
    const int kp  = swz / 320;
    const int rem = swz - kp * 320;
    const int bm  = rem >> 3;    // 0..39
    const int bn  = rem & 7;     // 0..7
    const int KSTEPS = 512 / KSP;
    const int kbase  = kp * (S_DIM / KSP);

    const int t  = threadIdx.x;
    const int l  = t & 63;
    const int wm = (t >> 7) & 1;
    const int wn = (t >> 6) & 1;
    const int lr = l & 15;
    const int kq = l >> 4;

    const ushort* Ablk  = A + (size_t)(bm * 128) * S_DIM + kbase;
    const ushort* Blane = BT + (size_t)(bn * 128 + wn * 64 + lr) * S_DIM +
                          kbase + kq * 8;

    bf16x8 b0[4], b1[4];
    f32x4 acc[4][4];
#pragma unroll
    for (int i = 0; i < 4; ++i)
#pragma unroll
        for (int j = 0; j < 4; ++j) acc[i][j] = (f32x4)0.f;

    // A tile 128x32 bf16 = 512 16B-chunks; LDS slot sl of row r holds global
    // chunk sl ^ ((r>>1)&3); DMA dest linear. 2 loads/thread/step.
#define STAGE_A(BUF, S)                                                         \
    { _Pragma("unroll") for (int i = 0; i < 2; ++i) {                           \
        const int cch = i * 256 + t;                                            \
        const int r = cch >> 2, sl = cch & 3;                                   \
        const ushort* gp = Ablk + (size_t)r * S_DIM + (S) * 32 +                \
                           ((sl ^ ((r >> 1) & 3)) << 3);                        \
        ushort* lp = &As[BUF][(i * 256 + (t & 192)) * 8];                       \
        __builtin_amdgcn_global_load_lds(                                       \
            (const __attribute__((address_space(1))) void*)gp,                  \
            (__attribute__((address_space(3))) void*)lp, 16, 0, 0);             \
      } }

#define LOAD_B(RG, S)                                                           \
    { _Pragma("unroll") for (int ni = 0; ni < 4; ++ni)                          \
        RG[ni] = *reinterpret_cast<const bf16x8*>(                              \
            Blane + (size_t)ni * 16 * S_DIM + (size_t)(S) * 32);                \
    }

#define COMPUTE(BUF, RG)                                                        \
    { bf16x8 fa[4];                                                             \
      _Pragma("unroll") for (int mi = 0; mi < 4; ++mi) {                        \
        const int r = wm * 64 + mi * 16 + lr;                                   \
        fa[mi] = *reinterpret_cast<const bf16x8*>(                              \
            &As[BUF][(r * 4 + (kq ^ ((r >> 1) & 3))) * 8]);                     \
      }                                                                         \
      _Pragma("unroll") for (int ni = 0; ni < 4; ++ni)                          \
        _Pragma("unroll") for (int mi = 0; mi < 4; ++mi)                        \
          acc[mi][ni] = __builtin_amdgcn_mfma_f32_16x16x32_bf16(                \
              fa[mi], RG[ni], acc[mi][ni], 0, 0, 0);                            \
    }

    // prologue: A0,A1 staged (4 loads), B0 in regs (4 loads).
    STAGE_A(0, 0)
    STAGE_A(1, 1)
    LOAD_B(b0, 0)
    asm volatile("s_waitcnt vmcnt(6)" ::: "memory");   // A0 landed
    __builtin_amdgcn_s_barrier();
    __builtin_amdgcn_sched_barrier(0);

    const int NIT = (KSTEPS - 2) / 2;   // covers s = 0 .. KSTEPS-3
    for (int s2 = 0; s2 < NIT; ++s2) {
        const int s = 2 * s2;
        // even: compute s (b0), stage s+2, load B(s+1) into b1
        STAGE_A((s + 2) % 3, s + 2)
        LOAD_B(b1, s + 1)
        __builtin_amdgcn_s_setprio(1);
        COMPUTE(s % 3, b0)
        __builtin_amdgcn_s_setprio(0);
        __builtin_amdgcn_sched_barrier(0);
        asm volatile("s_waitcnt vmcnt(6)" ::: "memory");  // A(s+1) landed
        __builtin_amdgcn_s_barrier();
        __builtin_amdgcn_sched_barrier(0);
        // odd: compute s+1 (b1), stage s+3, load B(s+2) into b0
        STAGE_A((s + 3) % 3, s + 3)
        LOAD_B(b0, s + 2)
        __builtin_amdgcn_s_setprio(1);
        COMPUTE((s + 1) % 3, b1)
        __builtin_amdgcn_s_setprio(0);
        __builtin_amdgcn_sched_barrier(0);
        asm volatile("s_waitcnt vmcnt(6)" ::: "memory");
        __builtin_amdgcn_s_barrier();
        __builtin_amdgcn_sched_barrier(0);
    }
    // tail: s = KSTEPS-2, KSTEPS-1 (all A staged; b0 holds B(KSTEPS-2))
    {
        LOAD_B(b1, KSTEPS - 1)
        __builtin_amdgcn_s_setprio(1);
        COMPUTE((KSTEPS - 2) % 3, b0)
        __builtin_amdgcn_s_setprio(0);
        __builtin_amdgcn_sched_barrier(0);
        asm volatile("s_waitcnt vmcnt(4)" ::: "memory");  // A(KSTEPS-1) landed
        __builtin_amdgcn_s_barrier();
        __builtin_amdgcn_sched_barrier(0);
        COMPUTE((KSTEPS - 1) % 3, b1)
    }

    // epilogue: bf16 slab kp. C/D layout col=lane&15, row=(lane>>4)*4+reg.
    ushort* C = Cout + (size_t)kp * PHI_ELEMS;
#pragma unroll
    for (int mi = 0; mi < 4; ++mi) {
        int orow = bm * 128 + wm * 64 + mi * 16 + kq * 4;
#pragma unroll
        for (int ni = 0; ni < 4; ++ni) {
            int ocol = bn * 128 + wn * 64 + ni * 16 + lr;
            ushort* cp = C + (size_t)orow * K_DIM + ocol;
#pragma unroll
            for (int rr = 0; rr < 4; ++rr)
                cp[(size_t)rr * K_DIM] = f2bfu(acc[mi][ni][rr]);
        }
    }
#undef STAGE_A
#undef LOAD_B
#undef COMPUTE
}

// ---------------- gemm_bb: verified r7 kernel, used for T = phib x G ---------
template <int SD, int KSP>
__global__ __launch_bounds__(256, 3) void gemm_bb(const ushort* __restrict__ A,
                                                  const ushort* __restrict__ BT,
                                                  float* __restrict__ Cout) {
    __shared__ ushort As[3][4096];
    __shared__ ushort Bs[3][4096];

    const int nwg = 320 * KSP;
    const int lid = blockIdx.x;
    const int swz = (lid & 7) * (nwg >> 3) + (lid >> 3);
    const int kp  = swz / 320;
    const int rem = swz - kp * 320;
    const int bm  = rem >> 3;
    const int bn  = rem & 7;
    const int KSTEPS = SD / 32 / KSP;
    const int kbase  = kp * (SD / KSP);

    const int t  = threadIdx.x;
    const int l  = t & 63;
    const int wm = (t >> 7) & 1;
    const int wn = (t >> 6) & 1;
    const int lr = l & 15;
    const int kq = l >> 4;

    const ushort* Ablk = A  + (size_t)(bm * 128) * SD + kbase;
    const ushort* Bblk = BT + (size_t)(bn * 128) * SD + kbase;

    f32x4 acc[4][4];
#pragma unroll
    for (int i = 0; i < 4; ++i)
#pragma unroll
        for (int j = 0; j < 4; ++j) acc[i][j] = (f32x4)0.f;

#define GSTAGE(BUF, S, SRC, DST)                                                \
    { _Pragma("unroll") for (int i = 0; i < 2; ++i) {                           \
        const int cch = i * 256 + t;                                            \
        const int r = cch >> 2, sl = cch & 3;                                   \
        const ushort* gp = SRC + (size_t)r * SD + (S) * 32 +                    \
                           ((sl ^ ((r >> 1) & 3)) << 3);                        \
        ushort* lp = &DST[BUF][(i * 256 + (t & 192)) * 8];                      \
        __builtin_amdgcn_global_load_lds(                                       \
            (const __attribute__((address_space(1))) void*)gp,                  \
            (__attribute__((address_space(3))) void*)lp, 16, 0, 0);             \
      } }

#define GCOMPUTE(BUF)                                                           \
    { bf16x8 fa[4], fb[4];                                                      \
      _Pragma("unroll") for (int mi = 0; mi < 4; ++mi) {                        \
        const int r = wm * 64 + mi * 16 + lr;                                   \
        fa[mi] = *reinterpret_cast<const bf16x8*>(                              \
            &As[BUF][(r * 4 + (kq ^ ((r >> 1) & 3))) * 8]);                     \
      }                                                                         \
      _Pragma("unroll") for (int ni = 0; ni < 4; ++ni) {                        \
        const int c = wn * 64 + ni * 16 + lr;                                   \
        fb[ni] = *reinterpret_cast<const bf16x8*>(                              \
            &Bs[BUF][(c * 4 + (kq ^ ((c >> 1) & 3))) * 8]);                     \
      }                                                                         \
      _Pragma("unroll") for (int ni = 0; ni < 4; ++ni)                          \
        _Pragma("unroll") for (int mi = 0; mi < 4; ++mi)                        \
          acc[mi][ni] = __builtin_amdgcn_mfma_f32_16x16x32_bf16(                \
              fa[mi], fb[ni], acc[mi][ni], 0, 0, 0);                            \
    }

    GSTAGE(0, 0, Ablk, As)
    GSTAGE(0, 0, Bblk, Bs)
    GSTAGE(1, 1, Ablk, As)
    GSTAGE(1, 1, Bblk, Bs)
    asm volatile("s_waitcnt vmcnt(4)" ::: "memory");
    __builtin_amdgcn_s_barrier();
    __builtin_amdgcn_sched_barrier(0);

    for (int s = 0; s < KSTEPS - 2; ++s) {
        const int sb = (s + 2) % 3, cb = s % 3;
        GSTAGE(sb, s + 2, Ablk, As)
        GSTAGE(sb, s + 2, Bblk, Bs)
        __builtin_amdgcn_s_setprio(1);
        GCOMPUTE(cb)
        __builtin_amdgcn_s_setprio(0);
        __builtin_amdgcn_sched_barrier(0);
        asm volatile("s_waitcnt vmcnt(4)" ::: "memory");
        __builtin_amdgcn_s_barrier();
        __builtin_amdgcn_sched_barrier(0);
    }
    {
        __builtin_amdgcn_s_setprio(1);
        GCOMPUTE((KSTEPS - 2) % 3)
        __builtin_amdgcn_s_setprio(0);
        __builtin_amdgcn_sched_barrier(0);
        asm volatile("s_waitcnt vmcnt(0)" ::: "memory");
        __builtin_amdgcn_s_barrier();
        __builtin_amdgcn_sched_barrier(0);
        GCOMPUTE((KSTEPS - 1) % 3)
    }

    float* C = Cout + (size_t)kp * PHI_ELEMS;
#pragma unroll
    for (int mi = 0; mi < 4; ++mi) {
        int orow = bm * 128 + wm * 64 + mi * 16 + kq * 4;
#pragma unroll
        for (int ni = 0; ni < 4; ++ni) {
            int ocol = bn * 128 + wn * 64 + ni * 16 + lr;
            float* cp = C + (size_t)orow * K_DIM + ocol;
#pragma unroll
            for (int rr = 0; rr < 4; ++rr) cp[(size_t)rr * K_DIM] = acc[mi][ni][rr];
        }
    }
#undef GSTAGE
#undef GCOMPUTE
}

// ---------------- sum 8 bf16 partial slabs -> phib (bf16) --------------------
__global__ __launch_bounds__(256) void phi_reduce8(const ushort* __restrict__ slabs,
                                                   ushort* __restrict__ phib) {
    const int n8 = PHI_ELEMS / 8;
    for (int i = blockIdx.x * 256 + threadIdx.x; i < n8; i += gridDim.x * 256) {
        float s[8] = {0.f, 0.f, 0.f, 0.f, 0.f, 0.f, 0.f, 0.f};
#pragma unroll
        for (int p = 0; p < 8; ++p) {
            ushort8 u = reinterpret_cast<const ushort8*>(
                slabs + (size_t)p * PHI_ELEMS)[i];
#pragma unroll
            for (int j = 0; j < 8; ++j) s[j] += bfu2f(u[j]);
        }
        ushort8 o;
#pragma unroll
        for (int j = 0; j < 8; ++j) o[j] = f2bfu(s[j]);
        reinterpret_cast<ushort8*>(phib)[i] = o;
    }
}

// ---------------- var contract (bf16 P): var[n,a,b] = sum_g T[a,g] P[b,g] ---
__global__ __launch_bounds__(256) void var_contract_b(const float* __restrict__ T,
                                                      const ushort* __restrict__ P,
                                                      float* __restrict__ out) {
    __shared__ float red[4][56];
    const int n = blockIdx.x, t = threadIdx.x, lane = t & 63, wid = t >> 6;
    const float*  Tn = T + (size_t)n * D_CLS * K_DIM;
    const ushort* Pn = P + (size_t)n * D_CLS * K_DIM;
    float Ta[D_CLS][4], Pb[D_CLS][4];
#pragma unroll
    for (int a = 0; a < D_CLS; ++a)
#pragma unroll
        for (int j = 0; j < 4; ++j) {
            Ta[a][j] = Tn[a * K_DIM + t + 256 * j];
            Pb[a][j] = bfu2f(Pn[a * K_DIM + t + 256 * j]);
        }
    int p = 0;
#pragma unroll
    for (int a = 0; a < D_CLS; ++a)
#pragma unroll
        for (int b = 0; b <= a; ++b, ++p) {
            float s = Ta[a][0] * Pb[b][0] + Ta[a][1] * Pb[b][1]
                    + Ta[a][2] * Pb[b][2] + Ta[a][3] * Pb[b][3];
#pragma unroll
            for (int off = 32; off > 0; off >>= 1) s += __shfl_down(s, off);
            if (lane == 0) red[wid][p] = s;
        }
    __syncthreads();
    if (t < 55) {
        int a = 0;
        while ((a + 1) * (a + 2) / 2 <= t) ++a;
        int b = t - a * (a + 1) / 2;
        float s = red[0][t] + red[1][t] + red[2][t] + red[3][t];
        float* vout = out + M_PTS * D_CLS + (size_t)n * D_CLS * D_CLS;
        vout[a * D_CLS + b] = s;
        vout[b * D_CLS + a] = s;
    }
}

extern "C" void kernel_launch(void* const* d_in, const int* in_sizes, int n_in,
                              void* d_out, int out_size, void* d_ws, size_t ws_size,
                              hipStream_t stream) {
    const float* X  = (const float*)d_in[0];
    const float* Jz = (const float*)d_in[1];
    const float* v  = (const float*)d_in[2];
    const float* G  = (const float*)d_in[3];
    const float* W  = (const float*)d_in[4];
    float* out = (float*)d_out;
    float* ws  = (float*)d_ws;

    const size_t PHB  = (size_t)PHI_ELEMS * 2;               // 10.5 MB bf16 slab
    const size_t A_B  = (size_t)5120 * S_DIM * 2;            // Abf  167.8 MB
    const size_t BT_B = (size_t)K_DIM * S_DIM * 2;           // vTbf  33.6 MB
    const size_t G_B  = (size_t)K_DIM * K_DIM * 2;           // Gbf    2.1 MB
    const size_t NEW_NEED = 8 * PHB + BT_B + G_B + A_B;      // ~287.3 MB
    const size_t MID_NEED = 1 * PHB + BT_B + G_B + A_B;      // ~213.9 MB

    hipLaunchKernelGGL(mean_kernel, dim3(M_PTS), dim3(64), 0, stream, X, W, out);

    if (ws_size >= NEW_NEED) {
        ushort* slabs = (ushort*)ws;                          // 8 bf16 slabs
        ushort* vTb   = slabs + (size_t)8 * PHI_ELEMS;
        ushort* Gb    = vTb + (size_t)K_DIM * S_DIM;
        ushort* Abf   = Gb + (size_t)K_DIM * K_DIM;
        // After the big gemm, Abf (167.8 MB) is dead -> overlay phib + T.
        ushort* phib  = Abf;
        float*  T     = (float*)(Abf + (size_t)PHI_ELEMS);    // 21 MB, inside Abf

        hipLaunchKernelGGL(cvt_a, dim3(2048), dim3(256), 0, stream,
                           Jz, Abf, 5120 * S_DIM / 8);
        hipLaunchKernelGGL(cvt_bt, dim3(256, 16), dim3(256), 0, stream, v, vTb);
        hipLaunchKernelGGL(cvt_a, dim3(256), dim3(256), 0, stream,
                           G, Gb, K_DIM * K_DIM / 8);
        hipLaunchKernelGGL(gemm_bd<8>, dim3(2560), dim3(256), 0, stream,
                           Abf, vTb, slabs);
        hipLaunchKernelGGL(phi_reduce8, dim3(1024), dim3(256), 0, stream,
                           slabs, phib);
        hipLaunchKernelGGL((gemm_bb<K_DIM, 1>), dim3(320), dim3(256), 0, stream,
                           phib, Gb, T);
        hipLaunchKernelGGL(var_contract_b, dim3(M_PTS), dim3(256), 0, stream,
                           T, phib, out);
        return;
    }

    // MID path: KSP=1 -> single bf16 slab IS phib (no reduce pass)
    {
        ushort* phib = (ushort*)ws;
        ushort* vTb  = phib + (size_t)PHI_ELEMS;
        ushort* Gb   = vTb + (size_t)K_DIM * S_DIM;
        ushort* Abf  = Gb + (size_t)K_DIM * K_DIM;
        float*  T    = (float*)Abf;                           // overlay (dead after gemm)

        hipLaunchKernelGGL(cvt_a, dim3(2048), dim3(256), 0, stream,
                           Jz, Abf, 5120 * S_DIM / 8);
        hipLaunchKernelGGL(cvt_bt, dim3(256, 16), dim3(256), 0, stream, v, vTb);
        hipLaunchKernelGGL(cvt_a, dim3(256), dim3(256), 0, stream,
                           G, Gb, K_DIM * K_DIM / 8);
        hipLaunchKernelGGL(gemm_bd<1>, dim3(320), dim3(256), 0, stream,
                           Abf, vTb, phib);
        hipLaunchKernelGGL((gemm_bb<K_DIM, 1>), dim3(320), dim3(256), 0, stream,
                           phib, Gb, T);
        hipLaunchKernelGGL(var_contract_b, dim3(M_PTS), dim3(256), 0, stream,
                           T, phib, out);
    }
}

// Round 10
// 499.781 us; speedup vs baseline: 1.0889x; 1.0889x over previous
//
#include <hip/hip_runtime.h>
#include <hip/hip_bf16.h>

#define M_PTS 512
#define D_CLS 10
#define S_DIM 16384
#define K_DIM 1024
#define DIN_  784
#define PHI_ELEMS (5120 * 1024)

typedef short  bf16x8  __attribute__((ext_vector_type(8)));
typedef float  f32x4   __attribute__((ext_vector_type(4)));
typedef uint   uintx4  __attribute__((ext_vector_type(4)));
typedef ushort ushort8 __attribute__((ext_vector_type(8)));

__device__ __forceinline__ ushort f2bfu(float f) {
    __bf16 h = (__bf16)f;                 // hardware RNE cvt on gfx950
    return __builtin_bit_cast(ushort, h);
}
__device__ __forceinline__ float bfu2f(ushort u) {
    uint x = (uint)u << 16;
    return __builtin_bit_cast(float, x);
}
__device__ __forceinline__ uint pkbf(float a, float b) {
    return (uint)f2bfu(a) | ((uint)f2bfu(b) << 16);
}

// ---------------- mean = X @ W  (512x784 @ 784x10) ----------------
__global__ __launch_bounds__(64) void mean_kernel(const float* __restrict__ X,
                                                  const float* __restrict__ W,
                                                  float* __restrict__ out) {
    int m = blockIdx.x;
    int lane = threadIdx.x;
    float acc[D_CLS];
#pragma unroll
    for (int d = 0; d < D_CLS; ++d) acc[d] = 0.f;
    for (int i = lane; i < DIN_; i += 64) {
        float x = X[(size_t)m * DIN_ + i];
#pragma unroll
        for (int d = 0; d < D_CLS; ++d) acc[d] += x * W[i * D_CLS + d];
    }
#pragma unroll
    for (int d = 0; d < D_CLS; ++d) {
        float v = acc[d];
        for (int off = 32; off > 0; off >>= 1) v += __shfl_down(v, off);
        if (lane == 0) out[(size_t)m * D_CLS + d] = v;
    }
}

// ---------------- f32 -> bf16 streaming convert (n8 = elems/8) ---------------
__global__ __launch_bounds__(256) void cvt_a(const float* __restrict__ src,
                                             ushort* __restrict__ dst, int n8) {
    for (int i = blockIdx.x * 256 + threadIdx.x; i < n8; i += gridDim.x * 256) {
        float4 a = reinterpret_cast<const float4*>(src)[2 * i];
        float4 b = reinterpret_cast<const float4*>(src)[2 * i + 1];
        ushort8 o;
        o[0] = f2bfu(a.x); o[1] = f2bfu(a.y); o[2] = f2bfu(a.z); o[3] = f2bfu(a.w);
        o[4] = f2bfu(b.x); o[5] = f2bfu(b.y); o[6] = f2bfu(b.z); o[7] = f2bfu(b.w);
        reinterpret_cast<ushort8*>(dst)[i] = o;
    }
}

// ---------------- v (16384x1024 f32) -> vT (1024x16384 bf16) -----------------
__global__ __launch_bounds__(256) void cvt_bt(const float* __restrict__ v,
                                              ushort* __restrict__ bt) {
    __shared__ float tile[64][65];
    const int kt = blockIdx.x;   // 256 k-tiles
    const int ct = blockIdx.y;   // 16 col-tiles
    const int t  = threadIdx.x;
    const int col4 = t & 15, row = t >> 4;
#pragma unroll
    for (int i = 0; i < 4; ++i) {
        int r = row + 16 * i;
        float4 v4 = *reinterpret_cast<const float4*>(
            v + (size_t)(kt * 64 + r) * K_DIM + ct * 64 + col4 * 4);
        tile[r][col4 * 4 + 0] = v4.x; tile[r][col4 * 4 + 1] = v4.y;
        tile[r][col4 * 4 + 2] = v4.z; tile[r][col4 * 4 + 3] = v4.w;
    }
    __syncthreads();
#pragma unroll
    for (int i = 0; i < 2; ++i) {
        int cid = i * 256 + t;
        int c = cid >> 3, kc = cid & 7;
        ushort8 o;
#pragma unroll
        for (int j = 0; j < 8; ++j) o[j] = f2bfu(tile[kc * 8 + j][c]);
        *reinterpret_cast<ushort8*>(bt + (size_t)(ct * 64 + c) * S_DIM +
                                    kt * 64 + kc * 8) = o;
    }
}

// ---------------- gemm_fa: fused-cvt GEMM ------------------------------------
// C(5120 x 1024) = bf16(A_f32)(5120 x 16384) x BT(1024 x 16384)^T.
// A is the RAW f32 Jz: staged to LDS via global_load_lds(16B), 8-slot swizzle
// sl^(r&7) (bank-balanced: group = slot mod 8, 16 rows x 4 kq -> uniform
// 8 lanes/group, 0 extra conflicts), converted f32->bf16 in-register after
// ds_read_b128 (pkbf x4 per fragment; hides in the 2-phase stall budget).
// This removes the 90 us cvt_a(Jz) streaming pass entirely.
// B: bf16 via verified r6/r7 path (4-slot swizzle (r>>1)&3, conflicts=0).
// Loop: r6's plain 2-buffer __syncthreads shape (48 KB LDS -> 3 blocks/CU).
// Writes bf16 partial slab kp (r8/r9-verified epilogue + reduce8 chain).
template <int KSP>
__global__ __launch_bounds__(256, 2) void gemm_fa(const float* __restrict__ A,
                                                  const ushort* __restrict__ BT,
                                                  ushort* __restrict__ Cout) {
    __shared__ float  As[2][4096];   // 128x32 f32 per buf (16 KB)
    __shared__ ushort Bs[2][4096];   // 128x32 bf16 per buf (8 KB)

    const int nwg = 320 * KSP;
    const int lid = blockIdx.x;
    const int swz = (lid & 7) * (nwg >> 3) + (lid >> 3);   // bijective XCD swizzle
    const int kp  = swz / 320;
    const int rem = swz - kp * 320;
    const int bm  = rem >> 3;    // 0..39
    const int bn  = rem & 7;     // 0..7
    const int KSTEPS = 512 / KSP;
    const int kbase  = kp * (S_DIM / KSP);

    const int t  = threadIdx.x;
    const int l  = t & 63;
    const int wm = (t >> 7) & 1;
    const int wn = (t >> 6) & 1;
    const int lr = l & 15;
    const int kq = l >> 4;

    const float*  Ablk = A  + (size_t)(bm * 128) * S_DIM + kbase;
    const ushort* Bblk = BT + (size_t)(bn * 128) * S_DIM + kbase;

    f32x4 acc[4][4];
#pragma unroll
    for (int i = 0; i < 4; ++i)
#pragma unroll
        for (int j = 0; j < 4; ++j) acc[i][j] = (f32x4)0.f;

    // A tile 128x32 f32 = 1024 16B-chunks (8/row). LDS slot sl of row r holds
    // global chunk sl ^ (r&7); DMA dest linear (wave-uniform base + lane*16B).
#define STAGE_A(BUF, S)                                                         \
    { _Pragma("unroll") for (int i = 0; i < 4; ++i) {                           \
        const int c = i * 256 + t;                                              \
        const int r = c >> 3, sl = c & 7;                                       \
        const float* gp = Ablk + (size_t)r * S_DIM + (S) * 32 +                 \
                          ((sl ^ (r & 7)) << 2);                                \
        float* lp = &As[BUF][(i * 256 + (t & 192)) << 2];                       \
        __builtin_amdgcn_global_load_lds(                                       \
            (const __attribute__((address_space(1))) void*)gp,                  \
            (__attribute__((address_space(3))) void*)lp, 16, 0, 0);             \
      } }

    // B tile 128x32 bf16 = 512 16B-chunks (4/row); slot sl holds chunk
    // sl ^ ((r>>1)&3)  (verified conflict-free r6/r7).
#define STAGE_B(BUF, S)                                                         \
    { _Pragma("unroll") for (int i = 0; i < 2; ++i) {                           \
        const int c = i * 256 + t;                                              \
        const int r = c >> 2, sl = c & 3;                                       \
        const ushort* gp = Bblk + (size_t)r * S_DIM + (S) * 32 +                \
                           ((sl ^ ((r >> 1) & 3)) << 3);                        \
        ushort* lp = &Bs[BUF][(i * 256 + (t & 192)) * 8];                       \
        __builtin_amdgcn_global_load_lds(                                       \
            (const __attribute__((address_space(1))) void*)gp,                  \
            (__attribute__((address_space(3))) void*)lp, 16, 0, 0);             \
      } }

#define COMPUTE(BUF)                                                            \
    { const f32x4* Av = reinterpret_cast<const f32x4*>(&As[BUF][0]);            \
      bf16x8 fa[4], fb[4];                                                      \
      _Pragma("unroll") for (int mi = 0; mi < 4; ++mi) {                        \
        const int r = wm * 64 + mi * 16 + lr;                                   \
        f32x4 a0 = Av[r * 8 + ((2 * kq) ^ (r & 7))];                            \
        f32x4 a1 = Av[r * 8 + ((2 * kq + 1) ^ (r & 7))];                        \
        uintx4 uu;                                                              \
        uu.x = pkbf(a0.x, a0.y); uu.y = pkbf(a0.z, a0.w);                       \
        uu.z = pkbf(a1.x, a1.y); uu.w = pkbf(a1.z, a1.w);                       \
        fa[mi] = __builtin_bit_cast(bf16x8, uu);                                \
      }                                                                         \
      _Pragma("unroll") for (int ni = 0; ni < 4; ++ni) {                        \
        const int c = wn * 64 + ni * 16 + lr;                                   \
        fb[ni] = *reinterpret_cast<const bf16x8*>(                              \
            &Bs[BUF][(c * 4 + (kq ^ ((c >> 1) & 3))) * 8]);                     \
      }                                                                         \
      _Pragma("unroll") for (int ni = 0; ni < 4; ++ni)                          \
        _Pragma("unroll") for (int mi = 0; mi < 4; ++mi)                        \
          acc[mi][ni] = __builtin_amdgcn_mfma_f32_16x16x32_bf16(                \
              fa[mi], fb[ni], acc[mi][ni], 0, 0, 0);                            \
    }

    STAGE_A(0, 0)
    STAGE_B(0, 0)
    __syncthreads();

    for (int s = 0; s < KSTEPS; ++s) {
        const int cb = s & 1, nb = cb ^ 1;
        if (s + 1 < KSTEPS) {
            STAGE_A(nb, s + 1)
            STAGE_B(nb, s + 1)
        }
        COMPUTE(cb)
        __syncthreads();
    }

    // epilogue: bf16 slab kp. C/D layout col=lane&15, row=(lane>>4)*4+reg.
    ushort* C = Cout + (size_t)kp * PHI_ELEMS;
#pragma unroll
    for (int mi = 0; mi < 4; ++mi) {
        int orow = bm * 128 + wm * 64 + mi * 16 + kq * 4;
#pragma unroll
        for (int ni = 0; ni < 4; ++ni) {
            int ocol = bn * 128 + wn * 64 + ni * 16 + lr;
            ushort* cp = C + (size_t)orow * K_DIM + ocol;
#pragma unroll
            for (int rr = 0; rr < 4; ++rr)
                cp[(size_t)rr * K_DIM] = f2bfu(acc[mi][ni][rr]);
        }
    }
#undef STAGE_A
#undef STAGE_B
#undef COMPUTE
}

// ---------------- gemm_bb: verified r7 kernel, used for T = phib x G ---------
template <int SD, int KSP>
__global__ __launch_bounds__(256, 3) void gemm_bb(const ushort* __restrict__ A,
                                                  const ushort* __restrict__ BT,
                                                  float* __restrict__ Cout) {
    __shared__ ushort As[3][4096];
    __shared__ ushort Bs[3][4096];

    const int nwg = 320 * KSP;
    const int lid = blockIdx.x;
    const int swz = (lid & 7) * (nwg >> 3) + (lid >> 3);
    const int kp  = swz / 320;
    const int rem = swz - kp * 320;
    const int bm  = rem >> 3;
    const int bn  = rem & 7;
    const int KSTEPS = SD / 32 / KSP;
    const int kbase  = kp * (SD / KSP);

    const int t  = threadIdx.x;
    const int l  = t & 63;
    const int wm = (t >> 7) & 1;
    const int wn = (t >> 6) & 1;
    const int lr = l & 15;
    const int kq = l >> 4;

    const ushort* Ablk = A  + (size_t)(bm * 128) * SD + kbase;
    const ushort* Bblk = BT + (size_t)(bn * 128) * SD + kbase;

    f32x4 acc[4][4];
#pragma unroll
    for (int i = 0; i < 4; ++i)
#pragma unroll
        for (int j = 0; j < 4; ++j) acc[i][j] = (f32x4)0.f;

#define GSTAGE(BUF, S, SRC, DST)                                                \
    { _Pragma("unroll") for (int i = 0; i < 2; ++i) {                           \
        const int cch = i * 256 + t;                                            \
        const int r = cch >> 2, sl = cch & 3;                                   \
        const ushort* gp = SRC + (size_t)r * SD + (S) * 32 +                    \
                           ((sl ^ ((r >> 1) & 3)) << 3);                        \
        ushort* lp = &DST[BUF][(i * 256 + (t & 192)) * 8];                      \
        __builtin_amdgcn_global_load_lds(                                       \
            (const __attribute__((address_space(1))) void*)gp,                  \
            (__attribute__((address_space(3))) void*)lp, 16, 0, 0);             \
      } }

#define GCOMPUTE(BUF)                                                           \
    { bf16x8 fa[4], fb[4];                                                      \
      _Pragma("unroll") for (int mi = 0; mi < 4; ++mi) {                        \
        const int r = wm * 64 + mi * 16 + lr;                                   \
        fa[mi] = *reinterpret_cast<const bf16x8*>(                              \
            &As[BUF][(r * 4 + (kq ^ ((r >> 1) & 3))) * 8]);                     \
      }                                                                         \
      _Pragma("unroll") for (int ni = 0; ni < 4; ++ni) {                        \
        const int c = wn * 64 + ni * 16 + lr;                                   \
        fb[ni] = *reinterpret_cast<const bf16x8*>(                              \
            &Bs[BUF][(c * 4 + (kq ^ ((c >> 1) & 3))) * 8]);                     \
      }                                                                         \
      _Pragma("unroll") for (int ni = 0; ni < 4; ++ni)                          \
        _Pragma("unroll") for (int mi = 0; mi < 4; ++mi)                        \
          acc[mi][ni] = __builtin_amdgcn_mfma_f32_16x16x32_bf16(                \
              fa[mi], fb[ni], acc[mi][ni], 0, 0, 0);                            \
    }

    GSTAGE(0, 0, Ablk, As)
    GSTAGE(0, 0, Bblk, Bs)
    GSTAGE(1, 1, Ablk, As)
    GSTAGE(1, 1, Bblk, Bs)
    asm volatile("s_waitcnt vmcnt(4)" ::: "memory");
    __builtin_amdgcn_s_barrier();
    __builtin_amdgcn_sched_barrier(0);

    for (int s = 0; s < KSTEPS - 2; ++s) {
        const int sb = (s + 2) % 3, cb = s % 3;
        GSTAGE(sb, s + 2, Ablk, As)
        GSTAGE(sb, s + 2, Bblk, Bs)
        __builtin_amdgcn_s_setprio(1);
        GCOMPUTE(cb)
        __builtin_amdgcn_s_setprio(0);
        __builtin_amdgcn_sched_barrier(0);
        asm volatile("s_waitcnt vmcnt(4)" ::: "memory");
        __builtin_amdgcn_s_barrier();
        __builtin_amdgcn_sched_barrier(0);
    }
    {
        __builtin_amdgcn_s_setprio(1);
        GCOMPUTE((KSTEPS - 2) % 3)
        __builtin_amdgcn_s_setprio(0);
        __builtin_amdgcn_sched_barrier(0);
        asm volatile("s_waitcnt vmcnt(0)" ::: "memory");
        __builtin_amdgcn_s_barrier();
        __builtin_amdgcn_sched_barrier(0);
        GCOMPUTE((KSTEPS - 1) % 3)
    }

    float* C = Cout + (size_t)kp * PHI_ELEMS;
#pragma unroll
    for (int mi = 0; mi < 4; ++mi) {
        int orow = bm * 128 + wm * 64 + mi * 16 + kq * 4;
#pragma unroll
        for (int ni = 0; ni < 4; ++ni) {
            int ocol = bn * 128 + wn * 64 + ni * 16 + lr;
            float* cp = C + (size_t)orow * K_DIM + ocol;
#pragma unroll
            for (int rr = 0; rr < 4; ++rr) cp[(size_t)rr * K_DIM] = acc[mi][ni][rr];
        }
    }
#undef GSTAGE
#undef GCOMPUTE
}

// ---------------- sum KSP bf16 partial slabs -> phib (bf16) ------------------
template <int KSP>
__global__ __launch_bounds__(256) void phi_reduceN(const ushort* __restrict__ slabs,
                                                   ushort* __restrict__ phib) {
    const int n8 = PHI_ELEMS / 8;
    for (int i = blockIdx.x * 256 + threadIdx.x; i < n8; i += gridDim.x * 256) {
        float s[8] = {0.f, 0.f, 0.f, 0.f, 0.f, 0.f, 0.f, 0.f};
#pragma unroll
        for (int p = 0; p < KSP; ++p) {
            ushort8 u = reinterpret_cast<const ushort8*>(
                slabs + (size_t)p * PHI_ELEMS)[i];
#pragma unroll
            for (int j = 0; j < 8; ++j) s[j] += bfu2f(u[j]);
        }
        ushort8 o;
#pragma unroll
        for (int j = 0; j < 8; ++j) o[j] = f2bfu(s[j]);
        reinterpret_cast<ushort8*>(phib)[i] = o;
    }
}

// ---------------- var contract (bf16 P): var[n,a,b] = sum_g T[a,g] P[b,g] ---
__global__ __launch_bounds__(256) void var_contract_b(const float* __restrict__ T,
                                                      const ushort* __restrict__ P,
                                                      float* __restrict__ out) {
    __shared__ float red[4][56];
    const int n = blockIdx.x, t = threadIdx.x, lane = t & 63, wid = t >> 6;
    const float*  Tn = T + (size_t)n * D_CLS * K_DIM;
    const ushort* Pn = P + (size_t)n * D_CLS * K_DIM;
    float Ta[D_CLS][4], Pb[D_CLS][4];
#pragma unroll
    for (int a = 0; a < D_CLS; ++a)
#pragma unroll
        for (int j = 0; j < 4; ++j) {
            Ta[a][j] = Tn[a * K_DIM + t + 256 * j];
            Pb[a][j] = bfu2f(Pn[a * K_DIM + t + 256 * j]);
        }
    int p = 0;
#pragma unroll
    for (int a = 0; a < D_CLS; ++a)
#pragma unroll
        for (int b = 0; b <= a; ++b, ++p) {
            float s = Ta[a][0] * Pb[b][0] + Ta[a][1] * Pb[b][1]
                    + Ta[a][2] * Pb[b][2] + Ta[a][3] * Pb[b][3];
#pragma unroll
            for (int off = 32; off > 0; off >>= 1) s += __shfl_down(s, off);
            if (lane == 0) red[wid][p] = s;
        }
    __syncthreads();
    if (t < 55) {
        int a = 0;
        while ((a + 1) * (a + 2) / 2 <= t) ++a;
        int b = t - a * (a + 1) / 2;
        float s = red[0][t] + red[1][t] + red[2][t] + red[3][t];
        float* vout = out + M_PTS * D_CLS + (size_t)n * D_CLS * D_CLS;
        vout[a * D_CLS + b] = s;
        vout[b * D_CLS + a] = s;
    }
}

extern "C" void kernel_launch(void* const* d_in, const int* in_sizes, int n_in,
                              void* d_out, int out_size, void* d_ws, size_t ws_size,
                              hipStream_t stream) {
    const float* X  = (const float*)d_in[0];
    const float* Jz = (const float*)d_in[1];
    const float* v  = (const float*)d_in[2];
    const float* G  = (const float*)d_in[3];
    const float* W  = (const float*)d_in[4];
    float* out = (float*)d_out;
    float* ws  = (float*)d_ws;

    const size_t PHB  = (size_t)PHI_ELEMS * 2;               // 10.5 MB bf16 slab
    const size_t BT_B = (size_t)K_DIM * S_DIM * 2;           // vTbf  33.6 MB
    const size_t G_B  = (size_t)K_DIM * K_DIM * 2;           // Gbf    2.1 MB
    // full path: 8 slabs + phib + T(f32) + vT + G  = ~151 MB
    const size_t FULL_NEED = 8 * PHB + PHB + (size_t)PHI_ELEMS * 4 + BT_B + G_B;
    // small path: 1 slab (=phib) + T + vT + G      = ~67 MB
    const size_t MIN_NEED  = PHB + (size_t)PHI_ELEMS * 4 + BT_B + G_B;

    hipLaunchKernelGGL(mean_kernel, dim3(M_PTS), dim3(64), 0, stream, X, W, out);

    if (ws_size >= FULL_NEED) {
        ushort* slabs = (ushort*)ws;                          // 8 bf16 slabs
        ushort* phib  = slabs + (size_t)8 * PHI_ELEMS;
        float*  T     = (float*)(phib + (size_t)PHI_ELEMS);
        ushort* vTb   = (ushort*)(T + (size_t)PHI_ELEMS);
        ushort* Gb    = vTb + (size_t)K_DIM * S_DIM;

        hipLaunchKernelGGL(cvt_bt, dim3(256, 16), dim3(256), 0, stream, v, vTb);
        hipLaunchKernelGGL(cvt_a, dim3(256), dim3(256), 0, stream,
                           G, Gb, K_DIM * K_DIM / 8);
        hipLaunchKernelGGL(gemm_fa<8>, dim3(2560), dim3(256), 0, stream,
                           Jz, vTb, slabs);
        hipLaunchKernelGGL(phi_reduceN<8>, dim3(1024), dim3(256), 0, stream,
                           slabs, phib);
        hipLaunchKernelGGL((gemm_bb<K_DIM, 1>), dim3(320), dim3(256), 0, stream,
                           phib, Gb, T);
        hipLaunchKernelGGL(var_contract_b, dim3(M_PTS), dim3(256), 0, stream,
                           T, phib, out);
        return;
    }

    // small-workspace path: KSP=1, the single slab IS phib (no reduce pass)
    {
        ushort* phib = (ushort*)ws;
        float*  T    = (float*)(phib + (size_t)PHI_ELEMS);
        ushort* vTb  = (ushort*)(T + (size_t)PHI_ELEMS);
        ushort* Gb   = vTb + (size_t)K_DIM * S_DIM;
        (void)MIN_NEED;

        hipLaunchKernelGGL(cvt_bt, dim3(256, 16), dim3(256), 0, stream, v, vTb);
        hipLaunchKernelGGL(cvt_a, dim3(256), dim3(256), 0, stream,
                           G, Gb, K_DIM * K_DIM / 8);
        hipLaunchKernelGGL(gemm_fa<1>, dim3(320), dim3(256), 0, stream,
                           Jz, vTb, phib);
        hipLaunchKernelGGL((gemm_bb<K_DIM, 1>), dim3(320), dim3(256), 0, stream,
                           phib, Gb, T);
        hipLaunchKernelGGL(var_contract_b, dim3(M_PTS), dim3(256), 0, stream,
                           T, phib, out);
    }
}

// Round 11
// 458.512 us; speedup vs baseline: 1.1869x; 1.0900x over previous
//
#include <hip/hip_runtime.h>
#include <hip/hip_bf16.h>

#define M_PTS 512
#define D_CLS 10
#define S_DIM 16384
#define K_DIM 1024
#define DIN_  784
#define PHI_ELEMS (5120 * 1024)

typedef short  bf16x8  __attribute__((ext_vector_type(8)));
typedef float  f32x4   __attribute__((ext_vector_type(4)));
typedef ushort ushort8 __attribute__((ext_vector_type(8)));

__device__ __forceinline__ ushort f2bfu(float f) {
    __bf16 h = (__bf16)f;                 // hardware RNE cvt on gfx950
    return __builtin_bit_cast(ushort, h);
}
__device__ __forceinline__ float bfu2f(ushort u) {
    uint x = (uint)u << 16;
    return __builtin_bit_cast(float, x);
}

// ---------------- mean = X @ W  (512x784 @ 784x10) ----------------
__global__ __launch_bounds__(64) void mean_kernel(const float* __restrict__ X,
                                                  const float* __restrict__ W,
                                                  float* __restrict__ out) {
    int m = blockIdx.x;
    int lane = threadIdx.x;
    float acc[D_CLS];
#pragma unroll
    for (int d = 0; d < D_CLS; ++d) acc[d] = 0.f;
    for (int i = lane; i < DIN_; i += 64) {
        float x = X[(size_t)m * DIN_ + i];
#pragma unroll
        for (int d = 0; d < D_CLS; ++d) acc[d] += x * W[i * D_CLS + d];
    }
#pragma unroll
    for (int d = 0; d < D_CLS; ++d) {
        float v = acc[d];
        for (int off = 32; off > 0; off >>= 1) v += __shfl_down(v, off);
        if (lane == 0) out[(size_t)m * D_CLS + d] = v;
    }
}

// ---------------- f32 -> bf16 streaming convert (n8 = elems/8) ---------------
__global__ __launch_bounds__(256) void cvt_a(const float* __restrict__ src,
                                             ushort* __restrict__ dst, int n8) {
    for (int i = blockIdx.x * 256 + threadIdx.x; i < n8; i += gridDim.x * 256) {
        float4 a = reinterpret_cast<const float4*>(src)[2 * i];
        float4 b = reinterpret_cast<const float4*>(src)[2 * i + 1];
        ushort8 o;
        o[0] = f2bfu(a.x); o[1] = f2bfu(a.y); o[2] = f2bfu(a.z); o[3] = f2bfu(a.w);
        o[4] = f2bfu(b.x); o[5] = f2bfu(b.y); o[6] = f2bfu(b.z); o[7] = f2bfu(b.w);
        reinterpret_cast<ushort8*>(dst)[i] = o;
    }
}

// ---------------- v (16384x1024 f32) -> vT (1024x16384 bf16) -----------------
__global__ __launch_bounds__(256) void cvt_bt(const float* __restrict__ v,
                                              ushort* __restrict__ bt) {
    __shared__ float tile[64][65];
    const int kt = blockIdx.x;   // 256 k-tiles
    const int ct = blockIdx.y;   // 16 col-tiles
    const int t  = threadIdx.x;
    const int col4 = t & 15, row = t >> 4;
#pragma unroll
    for (int i = 0; i < 4; ++i) {
        int r = row + 16 * i;
        float4 v4 = *reinterpret_cast<const float4*>(
            v + (size_t)(kt * 64 + r) * K_DIM + ct * 64 + col4 * 4);
        tile[r][col4 * 4 + 0] = v4.x; tile[r][col4 * 4 + 1] = v4.y;
        tile[r][col4 * 4 + 2] = v4.z; tile[r][col4 * 4 + 3] = v4.w;
    }
    __syncthreads();
#pragma unroll
    for (int i = 0; i < 2; ++i) {
        int cid = i * 256 + t;
        int c = cid >> 3, kc = cid & 7;
        ushort8 o;
#pragma unroll
        for (int j = 0; j < 8; ++j) o[j] = f2bfu(tile[kc * 8 + j][c]);
        *reinterpret_cast<ushort8*>(bt + (size_t)(ct * 64 + c) * S_DIM +
                                    kt * 64 + kc * 8) = o;
    }
}

// ---------------- gemm8p: 256x256 8-wave 4-phase/K-tile schedule -------------
// C(5120x1024) = A(5120x16384) x BT(1024x16384)^T, bf16 row-major.
// BM=BN=256, BK=64 stored as 2x [256][32]-bf16 sub-buffers (ks=0,1), each with
// the r6-VERIFIED conflict-free layout: slot sl of row r holds global chunk
// sl^((r>>1)&3) (avoids the empirically-conflicted 128B-row case, r4/r10).
// 512 thr = 8 waves (wm 0..1 x wn 0..3), wave tile 128x64, acc[8][4].
// Per K-tile: 4 phases (quadrant = M-half x K-half, Gray order):
//   P0(ks0,M0: ldB+ldA, stage A'ks0)  P1(ks0,M1: ldA, stage B'ks0, vmcnt(4))
//   P2(ks1,M1: ldB+ldA, stage A'ks1)  P3(ks1,M0: ldA, stage B'ks1, vmcnt(4))
// Each phase: {reads; stage; s_barrier; lgkmcnt(0); setprio(1); 16 MFMA;
// setprio(0); s_barrier}. vmcnt audit (2 loads/half-tile): at P1, outstanding
// = carryover{Aks1(s),Bks1(s)} (<=4) + 4 new -> vmcnt(4) drains carryover
// before P2 reads ks1. At P3: 8 this-iter -> vmcnt(4) lands {Aks0,Bks0}(s+1)
// needed at next P0. Buffer reuse: sub-buffer written in iter s was last READ
// in iter s-1 (completed via lgkmcnt+barrier before iter s began) -> race-free.
template <int KSP>
__global__ __launch_bounds__(512, 2) void gemm8p(const ushort* __restrict__ A,
                                                 const ushort* __restrict__ BT,
                                                 ushort* __restrict__ Cout) {
    __shared__ ushort As[2][2][8192];   // [dbuf][ks][256*32] = 64 KB
    __shared__ ushort Bs[2][2][8192];   // 64 KB  (128 KB total, 1 block/CU)

    const int nwg = 80 * KSP;
    const int lid = blockIdx.x;
    const int swz = (lid & 7) * (nwg >> 3) + (lid >> 3);   // bijective (nwg%8==0)
    const int kp  = swz / 80;
    const int rem = swz - kp * 80;
    const int bm  = rem >> 2;      // 0..19
    const int bn  = rem & 3;       // 0..3
    const int NIT = 256 / KSP;     // K-tiles of 64
    const int kbase = kp * (S_DIM / KSP);

    const int t  = threadIdx.x;
    const int l  = t & 63;
    const int w  = t >> 6;
    const int wm = w >> 2;         // 0..1
    const int wn = w & 3;          // 0..3
    const int lr = l & 15;
    const int kq = l >> 4;

    const ushort* Ablk = A  + (size_t)(bm * 256) * S_DIM + kbase;
    const ushort* Bblk = BT + (size_t)(bn * 256) * S_DIM + kbase;

    f32x4 acc[8][4];
#pragma unroll
    for (int i = 0; i < 8; ++i)
#pragma unroll
        for (int j = 0; j < 4; ++j) acc[i][j] = (f32x4)0.f;

    bf16x8 fa[4], fb[4];

    // one half-tile = [256][32] bf16 = 1024 chunks; 2 gload_lds per thread
#define STG(DSTBUF, SRC, KOFF)                                                  \
    { _Pragma("unroll") for (int i = 0; i < 2; ++i) {                           \
        const int c = i * 512 + t;                                              \
        const int r = c >> 2, sl = c & 3;                                       \
        const ushort* gp = SRC + (size_t)r * S_DIM + (KOFF) +                   \
                           ((sl ^ ((r >> 1) & 3)) << 3);                        \
        ushort* lp = &DSTBUF[(i * 512 + (t & 448)) * 8];                        \
        __builtin_amdgcn_global_load_lds(                                       \
            (const __attribute__((address_space(1))) void*)gp,                  \
            (__attribute__((address_space(3))) void*)lp, 16, 0, 0);             \
      } }

#define LDA(BUF, KS, MH)                                                        \
    { _Pragma("unroll") for (int mi = 0; mi < 4; ++mi) {                        \
        const int r = wm * 128 + (MH) * 64 + mi * 16 + lr;                      \
        fa[mi] = *reinterpret_cast<const bf16x8*>(                              \
            &As[BUF][KS][(r * 4 + (kq ^ ((r >> 1) & 3))) * 8]);                 \
      } }

#define LDB(BUF, KS)                                                            \
    { _Pragma("unroll") for (int ni = 0; ni < 4; ++ni) {                        \
        const int c = wn * 64 + ni * 16 + lr;                                   \
        fb[ni] = *reinterpret_cast<const bf16x8*>(                              \
            &Bs[BUF][KS][(c * 4 + (kq ^ ((c >> 1) & 3))) * 8]);                 \
      } }

#define MM(MH)                                                                  \
    { _Pragma("unroll") for (int ni = 0; ni < 4; ++ni)                          \
      _Pragma("unroll") for (int mi = 0; mi < 4; ++mi)                          \
        acc[(MH) * 4 + mi][ni] = __builtin_amdgcn_mfma_f32_16x16x32_bf16(       \
            fa[mi], fb[ni], acc[(MH) * 4 + mi][ni], 0, 0, 0); }

#define PHASE_SYNC_PRE                                                          \
    __builtin_amdgcn_s_barrier();                                               \
    asm volatile("s_waitcnt lgkmcnt(0)" ::: "memory");                          \
    __builtin_amdgcn_sched_barrier(0);                                          \
    __builtin_amdgcn_s_setprio(1);

#define PHASE_SYNC_POST                                                         \
    __builtin_amdgcn_s_setprio(0);                                              \
    __builtin_amdgcn_sched_barrier(0);

    // prologue: all 4 half-tiles of K-tile 0; vmcnt(4) -> ks0 halves landed
    STG(As[0][0], Ablk, 0)
    STG(Bs[0][0], Bblk, 0)
    STG(As[0][1], Ablk, 32)
    STG(Bs[0][1], Bblk, 32)
    asm volatile("s_waitcnt vmcnt(4)" ::: "memory");
    __builtin_amdgcn_s_barrier();
    __builtin_amdgcn_sched_barrier(0);

    for (int s = 0; s < NIT; ++s) {
        const int b = s & 1, nb = b ^ 1;
        const int kn = (s + 1) * 64;
        const bool st = (s + 1 < NIT);
        // ---- PHASE 0: ks0, M-half 0 ----
        LDB(b, 0)
        LDA(b, 0, 0)
        if (st) STG(As[nb][0], Ablk, kn)
        PHASE_SYNC_PRE
        MM(0)
        PHASE_SYNC_POST
        __builtin_amdgcn_s_barrier();
        // ---- PHASE 1: ks0, M-half 1 ----
        LDA(b, 0, 1)
        if (st) STG(Bs[nb][0], Bblk, kn)
        PHASE_SYNC_PRE
        MM(1)
        PHASE_SYNC_POST
        if (st) { asm volatile("s_waitcnt vmcnt(4)" ::: "memory"); }
        else    { asm volatile("s_waitcnt vmcnt(0)" ::: "memory"); }
        __builtin_amdgcn_s_barrier();
        // ---- PHASE 2: ks1, M-half 1 ----
        LDB(b, 1)
        LDA(b, 1, 1)
        if (st) STG(As[nb][1], Ablk, kn + 32)
        PHASE_SYNC_PRE
        MM(1)
        PHASE_SYNC_POST
        __builtin_amdgcn_s_barrier();
        // ---- PHASE 3: ks1, M-half 0 ----
        LDA(b, 1, 0)
        if (st) STG(Bs[nb][1], Bblk, kn + 32)
        PHASE_SYNC_PRE
        MM(0)
        PHASE_SYNC_POST
        if (st) { asm volatile("s_waitcnt vmcnt(4)" ::: "memory"); }
        __builtin_amdgcn_s_barrier();
    }

    // epilogue: bf16 slab kp. C/D layout col=lane&15, row=(lane>>4)*4+reg.
    ushort* C = Cout + (size_t)kp * PHI_ELEMS;
#pragma unroll
    for (int q = 0; q < 8; ++q) {
        int orow = bm * 256 + wm * 128 + (q >> 2) * 64 + (q & 3) * 16 + kq * 4;
#pragma unroll
        for (int ni = 0; ni < 4; ++ni) {
            int ocol = bn * 256 + wn * 64 + ni * 16 + lr;
            ushort* cp = C + (size_t)orow * K_DIM + ocol;
#pragma unroll
            for (int rr = 0; rr < 4; ++rr)
                cp[(size_t)rr * K_DIM] = f2bfu(acc[q][ni][rr]);
        }
    }
#undef STG
#undef LDA
#undef LDB
#undef MM
#undef PHASE_SYNC_PRE
#undef PHASE_SYNC_POST
}

// ---------------- gemm_bb: verified r7 kernel, used for T = phib x G ---------
template <int SD, int KSP>
__global__ __launch_bounds__(256, 3) void gemm_bb(const ushort* __restrict__ A,
                                                  const ushort* __restrict__ BT,
                                                  float* __restrict__ Cout) {
    __shared__ ushort As[3][4096];
    __shared__ ushort Bs[3][4096];

    const int nwg = 320 * KSP;
    const int lid = blockIdx.x;
    const int swz = (lid & 7) * (nwg >> 3) + (lid >> 3);
    const int kp  = swz / 320;
    const int rem = swz - kp * 320;
    const int bm  = rem >> 3;
    const int bn  = rem & 7;
    const int KSTEPS = SD / 32 / KSP;
    const int kbase  = kp * (SD / KSP);

    const int t  = threadIdx.x;
    const int l  = t & 63;
    const int wm = (t >> 7) & 1;
    const int wn = (t >> 6) & 1;
    const int lr = l & 15;
    const int kq = l >> 4;

    const ushort* Ablk = A  + (size_t)(bm * 128) * SD + kbase;
    const ushort* Bblk = BT + (size_t)(bn * 128) * SD + kbase;

    f32x4 acc[4][4];
#pragma unroll
    for (int i = 0; i < 4; ++i)
#pragma unroll
        for (int j = 0; j < 4; ++j) acc[i][j] = (f32x4)0.f;

#define GSTAGE(BUF, S, SRC, DST)                                                \
    { _Pragma("unroll") for (int i = 0; i < 2; ++i) {                           \
        const int cch = i * 256 + t;                                            \
        const int r = cch >> 2, sl = cch & 3;                                   \
        const ushort* gp = SRC + (size_t)r * SD + (S) * 32 +                    \
                           ((sl ^ ((r >> 1) & 3)) << 3);                        \
        ushort* lp = &DST[BUF][(i * 256 + (t & 192)) * 8];                      \
        __builtin_amdgcn_global_load_lds(                                       \
            (const __attribute__((address_space(1))) void*)gp,                  \
            (__attribute__((address_space(3))) void*)lp, 16, 0, 0);             \
      } }

#define GCOMPUTE(BUF)                                                           \
    { bf16x8 fa[4], fb[4];                                                      \
      _Pragma("unroll") for (int mi = 0; mi < 4; ++mi) {                        \
        const int r = wm * 64 + mi * 16 + lr;                                   \
        fa[mi] = *reinterpret_cast<const bf16x8*>(                              \
            &As[BUF][(r * 4 + (kq ^ ((r >> 1) & 3))) * 8]);                     \
      }                                                                         \
      _Pragma("unroll") for (int ni = 0; ni < 4; ++ni) {                        \
        const int c = wn * 64 + ni * 16 + lr;                                   \
        fb[ni] = *reinterpret_cast<const bf16x8*>(                              \
            &Bs[BUF][(c * 4 + (kq ^ ((c >> 1) & 3))) * 8]);                     \
      }                                                                         \
      _Pragma("unroll") for (int ni = 0; ni < 4; ++ni)                          \
        _Pragma("unroll") for (int mi = 0; mi < 4; ++mi)                        \
          acc[mi][ni] = __builtin_amdgcn_mfma_f32_16x16x32_bf16(                \
              fa[mi], fb[ni], acc[mi][ni], 0, 0, 0);                            \
    }

    GSTAGE(0, 0, Ablk, As)
    GSTAGE(0, 0, Bblk, Bs)
    GSTAGE(1, 1, Ablk, As)
    GSTAGE(1, 1, Bblk, Bs)
    asm volatile("s_waitcnt vmcnt(4)" ::: "memory");
    __builtin_amdgcn_s_barrier();
    __builtin_amdgcn_sched_barrier(0);

    for (int s = 0; s < KSTEPS - 2; ++s) {
        const int sb = (s + 2) % 3, cb = s % 3;
        GSTAGE(sb, s + 2, Ablk, As)
        GSTAGE(sb, s + 2, Bblk, Bs)
        __builtin_amdgcn_s_setprio(1);
        GCOMPUTE(cb)
        __builtin_amdgcn_s_setprio(0);
        __builtin_amdgcn_sched_barrier(0);
        asm volatile("s_waitcnt vmcnt(4)" ::: "memory");
        __builtin_amdgcn_s_barrier();
        __builtin_amdgcn_sched_barrier(0);
    }
    {
        __builtin_amdgcn_s_setprio(1);
        GCOMPUTE((KSTEPS - 2) % 3)
        __builtin_amdgcn_s_setprio(0);
        __builtin_amdgcn_sched_barrier(0);
        asm volatile("s_waitcnt vmcnt(0)" ::: "memory");
        __builtin_amdgcn_s_barrier();
        __builtin_amdgcn_sched_barrier(0);
        GCOMPUTE((KSTEPS - 1) % 3)
    }

    float* C = Cout + (size_t)kp * PHI_ELEMS;
#pragma unroll
    for (int mi = 0; mi < 4; ++mi) {
        int orow = bm * 128 + wm * 64 + mi * 16 + kq * 4;
#pragma unroll
        for (int ni = 0; ni < 4; ++ni) {
            int ocol = bn * 128 + wn * 64 + ni * 16 + lr;
            float* cp = C + (size_t)orow * K_DIM + ocol;
#pragma unroll
            for (int rr = 0; rr < 4; ++rr) cp[(size_t)rr * K_DIM] = acc[mi][ni][rr];
        }
    }
#undef GSTAGE
#undef GCOMPUTE
}

// ---------------- sum KSP bf16 partial slabs -> phib (may alias slab 0) ------
template <int KSP>
__global__ __launch_bounds__(256) void phi_reduceN(const ushort* __restrict__ slabs,
                                                   ushort* __restrict__ phib) {
    const int n8 = PHI_ELEMS / 8;
    for (int i = blockIdx.x * 256 + threadIdx.x; i < n8; i += gridDim.x * 256) {
        float s[8] = {0.f, 0.f, 0.f, 0.f, 0.f, 0.f, 0.f, 0.f};
#pragma unroll
        for (int p = 0; p < KSP; ++p) {
            ushort8 u = reinterpret_cast<const ushort8*>(
                slabs + (size_t)p * PHI_ELEMS)[i];
#pragma unroll
            for (int j = 0; j < 8; ++j) s[j] += bfu2f(u[j]);
        }
        ushort8 o;
#pragma unroll
        for (int j = 0; j < 8; ++j) o[j] = f2bfu(s[j]);
        reinterpret_cast<ushort8*>(phib)[i] = o;   // elementwise: alias-safe
    }
}

// ---------------- var contract (bf16 P): var[n,a,b] = sum_g T[a,g] P[b,g] ---
__global__ __launch_bounds__(256) void var_contract_b(const float* __restrict__ T,
                                                      const ushort* __restrict__ P,
                                                      float* __restrict__ out) {
    __shared__ float red[4][56];
    const int n = blockIdx.x, t = threadIdx.x, lane = t & 63, wid = t >> 6;
    const float*  Tn = T + (size_t)n * D_CLS * K_DIM;
    const ushort* Pn = P + (size_t)n * D_CLS * K_DIM;
    float Ta[D_CLS][4], Pb[D_CLS][4];
#pragma unroll
    for (int a = 0; a < D_CLS; ++a)
#pragma unroll
        for (int j = 0; j < 4; ++j) {
            Ta[a][j] = Tn[a * K_DIM + t + 256 * j];
            Pb[a][j] = bfu2f(Pn[a * K_DIM + t + 256 * j]);
        }
    int p = 0;
#pragma unroll
    for (int a = 0; a < D_CLS; ++a)
#pragma unroll
        for (int b = 0; b <= a; ++b, ++p) {
            float s = Ta[a][0] * Pb[b][0] + Ta[a][1] * Pb[b][1]
                    + Ta[a][2] * Pb[b][2] + Ta[a][3] * Pb[b][3];
#pragma unroll
            for (int off = 32; off > 0; off >>= 1) s += __shfl_down(s, off);
            if (lane == 0) red[wid][p] = s;
        }
    __syncthreads();
    if (t < 55) {
        int a = 0;
        while ((a + 1) * (a + 2) / 2 <= t) ++a;
        int b = t - a * (a + 1) / 2;
        float s = red[0][t] + red[1][t] + red[2][t] + red[3][t];
        float* vout = out + M_PTS * D_CLS + (size_t)n * D_CLS * D_CLS;
        vout[a * D_CLS + b] = s;
        vout[b * D_CLS + a] = s;
    }
}

extern "C" void kernel_launch(void* const* d_in, const int* in_sizes, int n_in,
                              void* d_out, int out_size, void* d_ws, size_t ws_size,
                              hipStream_t stream) {
    const float* X  = (const float*)d_in[0];
    const float* Jz = (const float*)d_in[1];
    const float* v  = (const float*)d_in[2];
    const float* G  = (const float*)d_in[3];
    const float* W  = (const float*)d_in[4];
    float* out = (float*)d_out;
    float* ws  = (float*)d_ws;

    const size_t PHB  = (size_t)PHI_ELEMS * 2;               // 10.5 MB bf16 slab
    const size_t A_B  = (size_t)5120 * S_DIM * 2;            // Abf  167.8 MB
    const size_t BT_B = (size_t)K_DIM * S_DIM * 2;           // vTbf  33.6 MB
    const size_t G_B  = (size_t)K_DIM * K_DIM * 2;           // Gbf    2.1 MB
    // overlays: phib aliases slab0 (elementwise reduce), T aliases slabs 2-3
    // (KSP>=4) or dead Abf (KSP=1), so NEED = slabs + vT + G + Abf.
    const size_t NEED8 = 8 * PHB + BT_B + G_B + A_B;         // ~287.5 MB (r9-proven)
    const size_t NEED4 = 4 * PHB + BT_B + G_B + A_B;         // ~245.5 MB
    const size_t NEED1 = 1 * PHB + BT_B + G_B + A_B;         // ~214 MB

    hipLaunchKernelGGL(mean_kernel, dim3(M_PTS), dim3(64), 0, stream, X, W, out);

    const int KSP = (ws_size >= NEED8) ? 8 : (ws_size >= NEED4) ? 4 : 1;
    ushort* slabs = (ushort*)ws;
    ushort* vTb   = slabs + (size_t)KSP * PHI_ELEMS;
    ushort* Gb    = vTb + (size_t)K_DIM * S_DIM;
    ushort* Abf   = Gb + (size_t)K_DIM * K_DIM;
    ushort* phib  = slabs;                                   // alias slab 0
    float*  T     = (KSP >= 4) ? (float*)(slabs + (size_t)2 * PHI_ELEMS)
                               : (float*)Abf;                // dead regions

    hipLaunchKernelGGL(cvt_a, dim3(2048), dim3(256), 0, stream,
                       Jz, Abf, 5120 * S_DIM / 8);
    hipLaunchKernelGGL(cvt_bt, dim3(256, 16), dim3(256), 0, stream, v, vTb);
    hipLaunchKernelGGL(cvt_a, dim3(256), dim3(256), 0, stream,
                       G, Gb, K_DIM * K_DIM / 8);
    if (KSP == 8) {
        hipLaunchKernelGGL(gemm8p<8>, dim3(640), dim3(512), 0, stream,
                           Abf, vTb, slabs);
        hipLaunchKernelGGL(phi_reduceN<8>, dim3(1024), dim3(256), 0, stream,
                           slabs, phib);
    } else if (KSP == 4) {
        hipLaunchKernelGGL(gemm8p<4>, dim3(320), dim3(512), 0, stream,
                           Abf, vTb, slabs);
        hipLaunchKernelGGL(phi_reduceN<4>, dim3(1024), dim3(256), 0, stream,
                           slabs, phib);
    } else {
        hipLaunchKernelGGL(gemm8p<1>, dim3(80), dim3(512), 0, stream,
                           Abf, vTb, slabs);                 // slab0 == phib
    }
    hipLaunchKernelGGL((gemm_bb<K_DIM, 1>), dim3(320), dim3(256), 0, stream,
                       phib, Gb, T);
    hipLaunchKernelGGL(var_contract_b, dim3(M_PTS), dim3(256), 0, stream,
                       T, phib, out);
}

// Round 12
// 408.837 us; speedup vs baseline: 1.3311x; 1.1215x over previous
//
#include <hip/hip_runtime.h>
#include <hip/hip_bf16.h>

#define M_PTS 512
#define D_CLS 10
#define S_DIM 16384
#define K_DIM 1024
#define DIN_  784
#define PHI_ELEMS (5120 * 1024)

typedef short  bf16x8  __attribute__((ext_vector_type(8)));
typedef float  f32x4   __attribute__((ext_vector_type(4)));
typedef ushort ushort8 __attribute__((ext_vector_type(8)));

__device__ __forceinline__ ushort f2bfu(float f) {
    __bf16 h = (__bf16)f;                 // hardware RNE cvt on gfx950
    return __builtin_bit_cast(ushort, h);
}
__device__ __forceinline__ float bfu2f(ushort u) {
    uint x = (uint)u << 16;
    return __builtin_bit_cast(float, x);
}

// ---------------- mean = X @ W  (512x784 @ 784x10) ----------------
__global__ __launch_bounds__(64) void mean_kernel(const float* __restrict__ X,
                                                  const float* __restrict__ W,
                                                  float* __restrict__ out) {
    int m = blockIdx.x;
    int lane = threadIdx.x;
    float acc[D_CLS];
#pragma unroll
    for (int d = 0; d < D_CLS; ++d) acc[d] = 0.f;
    for (int i = lane; i < DIN_; i += 64) {
        float x = X[(size_t)m * DIN_ + i];
#pragma unroll
        for (int d = 0; d < D_CLS; ++d) acc[d] += x * W[i * D_CLS + d];
    }
#pragma unroll
    for (int d = 0; d < D_CLS; ++d) {
        float v = acc[d];
        for (int off = 32; off > 0; off >>= 1) v += __shfl_down(v, off);
        if (lane == 0) out[(size_t)m * D_CLS + d] = v;
    }
}

// ---------------- f32 -> bf16 streaming convert (n8 = elems/8) ---------------
__global__ __launch_bounds__(256) void cvt_a(const float* __restrict__ src,
                                             ushort* __restrict__ dst, int n8) {
    for (int i = blockIdx.x * 256 + threadIdx.x; i < n8; i += gridDim.x * 256) {
        float4 a = reinterpret_cast<const float4*>(src)[2 * i];
        float4 b = reinterpret_cast<const float4*>(src)[2 * i + 1];
        ushort8 o;
        o[0] = f2bfu(a.x); o[1] = f2bfu(a.y); o[2] = f2bfu(a.z); o[3] = f2bfu(a.w);
        o[4] = f2bfu(b.x); o[5] = f2bfu(b.y); o[6] = f2bfu(b.z); o[7] = f2bfu(b.w);
        reinterpret_cast<ushort8*>(dst)[i] = o;
    }
}

// ---------------- v (16384x1024 f32) -> vT (1024x16384 bf16) -----------------
__global__ __launch_bounds__(256) void cvt_bt(const float* __restrict__ v,
                                              ushort* __restrict__ bt) {
    __shared__ float tile[64][65];
    const int kt = blockIdx.x;   // 256 k-tiles
    const int ct = blockIdx.y;   // 16 col-tiles
    const int t  = threadIdx.x;
    const int col4 = t & 15, row = t >> 4;
#pragma unroll
    for (int i = 0; i < 4; ++i) {
        int r = row + 16 * i;
        float4 v4 = *reinterpret_cast<const float4*>(
            v + (size_t)(kt * 64 + r) * K_DIM + ct * 64 + col4 * 4);
        tile[r][col4 * 4 + 0] = v4.x; tile[r][col4 * 4 + 1] = v4.y;
        tile[r][col4 * 4 + 2] = v4.z; tile[r][col4 * 4 + 3] = v4.w;
    }
    __syncthreads();
#pragma unroll
    for (int i = 0; i < 2; ++i) {
        int cid = i * 256 + t;
        int c = cid >> 3, kc = cid & 7;
        ushort8 o;
#pragma unroll
        for (int j = 0; j < 8; ++j) o[j] = f2bfu(tile[kc * 8 + j][c]);
        *reinterpret_cast<ushort8*>(bt + (size_t)(ct * 64 + c) * S_DIM +
                                    kt * 64 + kc * 8) = o;
    }
}

// ---------------- gemm_bs: r7-verified 128x128 depth-3 kernel, bf16 C out ----
// C(5120 x 1024) = A(5120 x SD) x BT(1024 x SD)^T, bf16 row-major [*][SD].
// BK=32, 256 threads = 4 waves (2M x 2N), wave tile 64x64.
// LDS swizzle f(r)=(r>>1)&3 (conflict-free, verified r6/r7: SQ_LDS_BANK_
// CONFLICT = 0). Depth-3 pipeline, counted vmcnt(4): tile s+2 stays in
// flight across barriers; never drains to 0 mid-loop. Measured 255 us (r7).
// Epilogue writes bf16 partial slab kp (r8/r9-verified chain).
template <int SD, int KSP>
__global__ __launch_bounds__(256, 3) void gemm_bs(const ushort* __restrict__ A,
                                                  const ushort* __restrict__ BT,
                                                  ushort* __restrict__ Cout) {
    __shared__ ushort As[3][4096];   // 8 KB per buf
    __shared__ ushort Bs[3][4096];   // 48 KB total -> 3 blocks/CU

    const int nwg = 320 * KSP;
    const int lid = blockIdx.x;
    const int swz = (lid & 7) * (nwg >> 3) + (lid >> 3);   // bijective XCD swizzle
    const int kp  = swz / 320;
    const int rem = swz - kp * 320;
    const int bm  = rem >> 3;    // 0..39
    const int bn  = rem & 7;     // 0..7
    const int KSTEPS = SD / 32 / KSP;
    const int kbase  = kp * (SD / KSP);

    const int t  = threadIdx.x;
    const int l  = t & 63;
    const int wm = (t >> 7) & 1;
    const int wn = (t >> 6) & 1;
    const int lr = l & 15;
    const int kq = l >> 4;

    const ushort* Ablk = A  + (size_t)(bm * 128) * SD + kbase;
    const ushort* Bblk = BT + (size_t)(bn * 128) * SD + kbase;

    f32x4 acc[4][4];
#pragma unroll
    for (int i = 0; i < 4; ++i)
#pragma unroll
        for (int j = 0; j < 4; ++j) acc[i][j] = (f32x4)0.f;

#define GSTAGE(BUF, S, SRC, DST)                                                \
    { _Pragma("unroll") for (int i = 0; i < 2; ++i) {                           \
        const int cch = i * 256 + t;                                            \
        const int r = cch >> 2, sl = cch & 3;                                   \
        const ushort* gp = SRC + (size_t)r * SD + (S) * 32 +                    \
                           ((sl ^ ((r >> 1) & 3)) << 3);                        \
        ushort* lp = &DST[BUF][(i * 256 + (t & 192)) * 8];                      \
        __builtin_amdgcn_global_load_lds(                                       \
            (const __attribute__((address_space(1))) void*)gp,                  \
            (__attribute__((address_space(3))) void*)lp, 16, 0, 0);             \
      } }

#define GCOMPUTE(BUF)                                                           \
    { bf16x8 fa[4], fb[4];                                                      \
      _Pragma("unroll") for (int mi = 0; mi < 4; ++mi) {                        \
        const int r = wm * 64 + mi * 16 + lr;                                   \
        fa[mi] = *reinterpret_cast<const bf16x8*>(                              \
            &As[BUF][(r * 4 + (kq ^ ((r >> 1) & 3))) * 8]);                     \
      }                                                                         \
      _Pragma("unroll") for (int ni = 0; ni < 4; ++ni) {                        \
        const int c = wn * 64 + ni * 16 + lr;                                   \
        fb[ni] = *reinterpret_cast<const bf16x8*>(                              \
            &Bs[BUF][(c * 4 + (kq ^ ((c >> 1) & 3))) * 8]);                     \
      }                                                                         \
      _Pragma("unroll") for (int ni = 0; ni < 4; ++ni)                          \
        _Pragma("unroll") for (int mi = 0; mi < 4; ++mi)                        \
          acc[mi][ni] = __builtin_amdgcn_mfma_f32_16x16x32_bf16(                \
              fa[mi], fb[ni], acc[mi][ni], 0, 0, 0);                            \
    }

    GSTAGE(0, 0, Ablk, As)
    GSTAGE(0, 0, Bblk, Bs)
    GSTAGE(1, 1, Ablk, As)
    GSTAGE(1, 1, Bblk, Bs)
    asm volatile("s_waitcnt vmcnt(4)" ::: "memory");
    __builtin_amdgcn_s_barrier();
    __builtin_amdgcn_sched_barrier(0);

    for (int s = 0; s < KSTEPS - 2; ++s) {
        const int sb = (s + 2) % 3, cb = s % 3;
        GSTAGE(sb, s + 2, Ablk, As)
        GSTAGE(sb, s + 2, Bblk, Bs)
        __builtin_amdgcn_s_setprio(1);
        GCOMPUTE(cb)
        __builtin_amdgcn_s_setprio(0);
        __builtin_amdgcn_sched_barrier(0);
        asm volatile("s_waitcnt vmcnt(4)" ::: "memory");
        __builtin_amdgcn_s_barrier();
        __builtin_amdgcn_sched_barrier(0);
    }
    {
        __builtin_amdgcn_s_setprio(1);
        GCOMPUTE((KSTEPS - 2) % 3)
        __builtin_amdgcn_s_setprio(0);
        __builtin_amdgcn_sched_barrier(0);
        asm volatile("s_waitcnt vmcnt(0)" ::: "memory");
        __builtin_amdgcn_s_barrier();
        __builtin_amdgcn_sched_barrier(0);
        GCOMPUTE((KSTEPS - 1) % 3)
    }

    // epilogue: bf16 slab kp. C/D layout col=lane&15, row=(lane>>4)*4+reg.
    ushort* C = Cout + (size_t)kp * PHI_ELEMS;
#pragma unroll
    for (int mi = 0; mi < 4; ++mi) {
        int orow = bm * 128 + wm * 64 + mi * 16 + kq * 4;
#pragma unroll
        for (int ni = 0; ni < 4; ++ni) {
            int ocol = bn * 128 + wn * 64 + ni * 16 + lr;
            ushort* cp = C + (size_t)orow * K_DIM + ocol;
#pragma unroll
            for (int rr = 0; rr < 4; ++rr)
                cp[(size_t)rr * K_DIM] = f2bfu(acc[mi][ni][rr]);
        }
    }
#undef GSTAGE
#undef GCOMPUTE
}

// ---------------- gemm_bb: identical structure, f32 C (T = phib x G) ---------
template <int SD, int KSP>
__global__ __launch_bounds__(256, 3) void gemm_bb(const ushort* __restrict__ A,
                                                  const ushort* __restrict__ BT,
                                                  float* __restrict__ Cout) {
    __shared__ ushort As[3][4096];
    __shared__ ushort Bs[3][4096];

    const int nwg = 320 * KSP;
    const int lid = blockIdx.x;
    const int swz = (lid & 7) * (nwg >> 3) + (lid >> 3);
    const int kp  = swz / 320;
    const int rem = swz - kp * 320;
    const int bm  = rem >> 3;
    const int bn  = rem & 7;
    const int KSTEPS = SD / 32 / KSP;
    const int kbase  = kp * (SD / KSP);

    const int t  = threadIdx.x;
    const int l  = t & 63;
    const int wm = (t >> 7) & 1;
    const int wn = (t >> 6) & 1;
    const int lr = l & 15;
    const int kq = l >> 4;

    const ushort* Ablk = A  + (size_t)(bm * 128) * SD + kbase;
    const ushort* Bblk = BT + (size_t)(bn * 128) * SD + kbase;

    f32x4 acc[4][4];
#pragma unroll
    for (int i = 0; i < 4; ++i)
#pragma unroll
        for (int j = 0; j < 4; ++j) acc[i][j] = (f32x4)0.f;

#define GSTAGE(BUF, S, SRC, DST)                                                \
    { _Pragma("unroll") for (int i = 0; i < 2; ++i) {                           \
        const int cch = i * 256 + t;                                            \
        const int r = cch >> 2, sl = cch & 3;                                   \
        const ushort* gp = SRC + (size_t)r * SD + (S) * 32 +                    \
                           ((sl ^ ((r >> 1) & 3)) << 3);                        \
        ushort* lp = &DST[BUF][(i * 256 + (t & 192)) * 8];                      \
        __builtin_amdgcn_global_load_lds(                                       \
            (const __attribute__((address_space(1))) void*)gp,                  \
            (__attribute__((address_space(3))) void*)lp, 16, 0, 0);             \
      } }

#define GCOMPUTE(BUF)                                                           \
    { bf16x8 fa[4], fb[4];                                                      \
      _Pragma("unroll") for (int mi = 0; mi < 4; ++mi) {                        \
        const int r = wm * 64 + mi * 16 + lr;                                   \
        fa[mi] = *reinterpret_cast<const bf16x8*>(                              \
            &As[BUF][(r * 4 + (kq ^ ((r >> 1) & 3))) * 8]);                     \
      }                                                                         \
      _Pragma("unroll") for (int ni = 0; ni < 4; ++ni) {                        \
        const int c = wn * 64 + ni * 16 + lr;                                   \
        fb[ni] = *reinterpret_cast<const bf16x8*>(                              \
            &Bs[BUF][(c * 4 + (kq ^ ((c >> 1) & 3))) * 8]);                     \
      }                                                                         \
      _Pragma("unroll") for (int ni = 0; ni < 4; ++ni)                          \
        _Pragma("unroll") for (int mi = 0; mi < 4; ++mi)                        \
          acc[mi][ni] = __builtin_amdgcn_mfma_f32_16x16x32_bf16(                \
              fa[mi], fb[ni], acc[mi][ni], 0, 0, 0);                            \
    }

    GSTAGE(0, 0, Ablk, As)
    GSTAGE(0, 0, Bblk, Bs)
    GSTAGE(1, 1, Ablk, As)
    GSTAGE(1, 1, Bblk, Bs)
    asm volatile("s_waitcnt vmcnt(4)" ::: "memory");
    __builtin_amdgcn_s_barrier();
    __builtin_amdgcn_sched_barrier(0);

    for (int s = 0; s < KSTEPS - 2; ++s) {
        const int sb = (s + 2) % 3, cb = s % 3;
        GSTAGE(sb, s + 2, Ablk, As)
        GSTAGE(sb, s + 2, Bblk, Bs)
        __builtin_amdgcn_s_setprio(1);
        GCOMPUTE(cb)
        __builtin_amdgcn_s_setprio(0);
        __builtin_amdgcn_sched_barrier(0);
        asm volatile("s_waitcnt vmcnt(4)" ::: "memory");
        __builtin_amdgcn_s_barrier();
        __builtin_amdgcn_sched_barrier(0);
    }
    {
        __builtin_amdgcn_s_setprio(1);
        GCOMPUTE((KSTEPS - 2) % 3)
        __builtin_amdgcn_s_setprio(0);
        __builtin_amdgcn_sched_barrier(0);
        asm volatile("s_waitcnt vmcnt(0)" ::: "memory");
        __builtin_amdgcn_s_barrier();
        __builtin_amdgcn_sched_barrier(0);
        GCOMPUTE((KSTEPS - 1) % 3)
    }

    float* C = Cout + (size_t)kp * PHI_ELEMS;
#pragma unroll
    for (int mi = 0; mi < 4; ++mi) {
        int orow = bm * 128 + wm * 64 + mi * 16 + kq * 4;
#pragma unroll
        for (int ni = 0; ni < 4; ++ni) {
            int ocol = bn * 128 + wn * 64 + ni * 16 + lr;
            float* cp = C + (size_t)orow * K_DIM + ocol;
#pragma unroll
            for (int rr = 0; rr < 4; ++rr) cp[(size_t)rr * K_DIM] = acc[mi][ni][rr];
        }
    }
#undef GSTAGE
#undef GCOMPUTE
}

// ---------------- sum KSP bf16 partial slabs -> phib (may alias slab 0) ------
template <int KSP>
__global__ __launch_bounds__(256) void phi_reduceN(const ushort* __restrict__ slabs,
                                                   ushort* __restrict__ phib) {
    const int n8 = PHI_ELEMS / 8;
    for (int i = blockIdx.x * 256 + threadIdx.x; i < n8; i += gridDim.x * 256) {
        float s[8] = {0.f, 0.f, 0.f, 0.f, 0.f, 0.f, 0.f, 0.f};
#pragma unroll
        for (int p = 0; p < KSP; ++p) {
            ushort8 u = reinterpret_cast<const ushort8*>(
                slabs + (size_t)p * PHI_ELEMS)[i];
#pragma unroll
            for (int j = 0; j < 8; ++j) s[j] += bfu2f(u[j]);
        }
        ushort8 o;
#pragma unroll
        for (int j = 0; j < 8; ++j) o[j] = f2bfu(s[j]);
        reinterpret_cast<ushort8*>(phib)[i] = o;   // elementwise: alias-safe
    }
}

// ---------------- var contract (bf16 P): var[n,a,b] = sum_g T[a,g] P[b,g] ---
__global__ __launch_bounds__(256) void var_contract_b(const float* __restrict__ T,
                                                      const ushort* __restrict__ P,
                                                      float* __restrict__ out) {
    __shared__ float red[4][56];
    const int n = blockIdx.x, t = threadIdx.x, lane = t & 63, wid = t >> 6;
    const float*  Tn = T + (size_t)n * D_CLS * K_DIM;
    const ushort* Pn = P + (size_t)n * D_CLS * K_DIM;
    float Ta[D_CLS][4], Pb[D_CLS][4];
#pragma unroll
    for (int a = 0; a < D_CLS; ++a)
#pragma unroll
        for (int j = 0; j < 4; ++j) {
            Ta[a][j] = Tn[a * K_DIM + t + 256 * j];
            Pb[a][j] = bfu2f(Pn[a * K_DIM + t + 256 * j]);
        }
    int p = 0;
#pragma unroll
    for (int a = 0; a < D_CLS; ++a)
#pragma unroll
        for (int b = 0; b <= a; ++b, ++p) {
            float s = Ta[a][0] * Pb[b][0] + Ta[a][1] * Pb[b][1]
                    + Ta[a][2] * Pb[b][2] + Ta[a][3] * Pb[b][3];
#pragma unroll
            for (int off = 32; off > 0; off >>= 1) s += __shfl_down(s, off);
            if (lane == 0) red[wid][p] = s;
        }
    __syncthreads();
    if (t < 55) {
        int a = 0;
        while ((a + 1) * (a + 2) / 2 <= t) ++a;
        int b = t - a * (a + 1) / 2;
        float s = red[0][t] + red[1][t] + red[2][t] + red[3][t];
        float* vout = out + M_PTS * D_CLS + (size_t)n * D_CLS * D_CLS;
        vout[a * D_CLS + b] = s;
        vout[b * D_CLS + a] = s;
    }
}

extern "C" void kernel_launch(void* const* d_in, const int* in_sizes, int n_in,
                              void* d_out, int out_size, void* d_ws, size_t ws_size,
                              hipStream_t stream) {
    const float* X  = (const float*)d_in[0];
    const float* Jz = (const float*)d_in[1];
    const float* v  = (const float*)d_in[2];
    const float* G  = (const float*)d_in[3];
    const float* W  = (const float*)d_in[4];
    float* out = (float*)d_out;
    float* ws  = (float*)d_ws;

    const size_t PHB  = (size_t)PHI_ELEMS * 2;               // 10.5 MB bf16 slab
    const size_t A_B  = (size_t)5120 * S_DIM * 2;            // Abf  167.8 MB
    const size_t BT_B = (size_t)K_DIM * S_DIM * 2;           // vTbf  33.6 MB
    const size_t G_B  = (size_t)K_DIM * K_DIM * 2;           // Gbf    2.1 MB
    // overlays: phib aliases slab0 (elementwise reduce, r11-verified); T
    // aliases slabs 2-3 (KSP=4, dead after reduce) or dead Abf (KSP=1).
    const size_t NEED4 = 4 * PHB + BT_B + G_B + A_B;         // ~245.5 MB
    const size_t NEED1 = 1 * PHB + BT_B + G_B + A_B;         // ~214 MB
    (void)NEED1;

    hipLaunchKernelGGL(mean_kernel, dim3(M_PTS), dim3(64), 0, stream, X, W, out);

    const int KSP = (ws_size >= NEED4) ? 4 : 1;
    ushort* slabs = (ushort*)ws;
    ushort* vTb   = slabs + (size_t)KSP * PHI_ELEMS;
    ushort* Gb    = vTb + (size_t)K_DIM * S_DIM;
    ushort* Abf   = Gb + (size_t)K_DIM * K_DIM;
    ushort* phib  = slabs;                                   // alias slab 0
    float*  T     = (KSP == 4) ? (float*)(slabs + (size_t)2 * PHI_ELEMS)
                               : (float*)Abf;                // dead regions

    hipLaunchKernelGGL(cvt_a, dim3(2048), dim3(256), 0, stream,
                       Jz, Abf, 5120 * S_DIM / 8);
    hipLaunchKernelGGL(cvt_bt, dim3(256, 16), dim3(256), 0, stream, v, vTb);
    hipLaunchKernelGGL(cvt_a, dim3(256), dim3(256), 0, stream,
                       G, Gb, K_DIM * K_DIM / 8);
    if (KSP == 4) {
        hipLaunchKernelGGL((gemm_bs<S_DIM, 4>), dim3(1280), dim3(256), 0,
                           stream, Abf, vTb, slabs);
        hipLaunchKernelGGL(phi_reduceN<4>, dim3(1024), dim3(256), 0, stream,
                           slabs, phib);
    } else {
        hipLaunchKernelGGL((gemm_bs<S_DIM, 1>), dim3(320), dim3(256), 0,
                           stream, Abf, vTb, slabs);         // slab0 == phib
    }
    hipLaunchKernelGGL((gemm_bb<K_DIM, 1>), dim3(320), dim3(256), 0, stream,
                       phib, Gb, T);
    hipLaunchKernelGGL(var_contract_b, dim3(M_PTS), dim3(256), 0, stream,
                       T, phib, out);
}